// Round 11
// baseline (3604.354 us; speedup 1.0000x reference)
//
#include <hip/hip_runtime.h>
#include <cstdint>

// Problem dims (fixed by reference)
#define B_   128
#define T_   32
#define IN_  2048
#define H_   2048
#define OUT_ 512

// ---------- kernel 1: transpose spikes ----------
__global__ __launch_bounds__(256) void k_transpose(const float* __restrict__ in,
                                                   float* __restrict__ Xt) {
    int idx = blockIdx.x * 256 + threadIdx.x;   // b*IN + i
    int b = idx >> 11;
    int i = idx & (IN_ - 1);
    const float4* p = (const float4*)(in + (size_t)idx * T_);
#pragma unroll
    for (int q = 0; q < 8; ++q) {
        float4 v = p[q];
        int t = q * 4;
        Xt[((size_t)((t + 0) * B_ + b) << 11) + i] = v.x;
        Xt[((size_t)((t + 1) * B_ + b) << 11) + i] = v.y;
        Xt[((size_t)((t + 2) * B_ + b) << 11) + i] = v.z;
        Xt[((size_t)((t + 3) * B_ + b) << 11) + i] = v.w;
    }
}

// ---------- kernel 2: fp32 GEMM, KC=512 chain (BLIS schedule), pipelined -----
// VERIFIED bit-exact vs ref (R10, absmax 0): per C element ascending-k fp32
// FMA chain, accumulator restarts at k=512/1024/1536, restart partials joined
// to C by plain rounded adds in ascending order. DO NOT change the chain.
// This version only restructures for throughput:
//  - register-buffered pipeline: next k0-tile's global loads issued right
//    after the staging barrier, consumed at the NEXT iteration's ds_write ->
//    global latency hidden under the ~2048-cyc compute window.
//  - thread tile TMxTN, 16x16 thread grid; BM=128/BN=64 for hidden GEMMs
//    (1024 blocks = 4/CU), VGPR budget <=128 for 4 waves/SIMD.
//  - LDS granule rotation: row r stores source granule s at slot ((s+rot(r))&7),
//    rot(r)=(r+(r>>4))&7 -> av reads distinct bank quads, wv reads 2-way (free).
template <int BM, int BN, int TM, int TN, int GA, int GW>
__global__ __launch_bounds__(256, 4)
void k_gemm_pipe(const float* __restrict__ A, const float* __restrict__ W,
                 float* __restrict__ C, int M, int N, int K) {
    __shared__ alignas(16) float At[BM * 32];
    __shared__ alignas(16) float Wt[BN * 32];

    const int tid = threadIdx.x;
    const int tx  = tid & 15;        // n direction
    const int ty  = tid >> 4;        // m direction
    const int m0  = blockIdx.y * BM;
    const int n0  = blockIdx.x * BN;

    float acc[TM][TN];               // in-block FMA chain (KC=512)
    float tot[TM][TN];               // cross-block joins (plain adds)
#pragma unroll
    for (int i = 0; i < TM; ++i)
#pragma unroll
        for (int j = 0; j < TN; ++j) { acc[i][j] = 0.0f; tot[i][j] = 0.0f; }

    float4 pa[GA], pw[GW];
    // prologue: load tile k0=0 into prefetch regs
#pragma unroll
    for (int u = 0; u < GA; ++u) {
        int g = tid + 256 * u, r = g >> 3, s = g & 7;
        pa[u] = *(const float4*)(A + (size_t)(m0 + r) * K + s * 4);
    }
#pragma unroll
    for (int u = 0; u < GW; ++u) {
        int g = tid + 256 * u, r = g >> 3, s = g & 7;
        pw[u] = *(const float4*)(W + (size_t)(n0 + r) * K + s * 4);
    }

    for (int k0 = 0; k0 < K; k0 += 32) {
        __syncthreads();             // previous compute done: LDS writable
        // stage prefetched regs -> LDS (rotated layout)
#pragma unroll
        for (int u = 0; u < GA; ++u) {
            int g = tid + 256 * u, r = g >> 3, s = g & 7;
            int rot = (r + (r >> 4)) & 7;
            *(float4*)&At[r * 32 + (((s + rot) & 7) << 2)] = pa[u];
        }
#pragma unroll
        for (int u = 0; u < GW; ++u) {
            int g = tid + 256 * u, r = g >> 3, s = g & 7;
            int rot = (r + (r >> 4)) & 7;
            *(float4*)&Wt[r * 32 + (((s + rot) & 7) << 2)] = pw[u];
        }
        __syncthreads();             // tile visible

        // issue NEXT tile's loads now; they fly under the compute below
        int kn = (k0 + 32 < K) ? (k0 + 32) : 0;   // last iter: harmless reload
#pragma unroll
        for (int u = 0; u < GA; ++u) {
            int g = tid + 256 * u, r = g >> 3, s = g & 7;
            pa[u] = *(const float4*)(A + (size_t)(m0 + r) * K + kn + s * 4);
        }
#pragma unroll
        for (int u = 0; u < GW; ++u) {
            int g = tid + 256 * u, r = g >> 3, s = g & 7;
            pw[u] = *(const float4*)(W + (size_t)(n0 + r) * K + kn + s * 4);
        }

        // compute: strictly ascending k, independent chain per C element
#pragma unroll
        for (int gk = 0; gk < 8; ++gk) {
            float4 av[TM], wv[TN];
#pragma unroll
            for (int i = 0; i < TM; ++i) {
                int r = ty + 16 * i;
                int rot = (r + (r >> 4)) & 7;
                av[i] = *(const float4*)&At[r * 32 + (((gk + rot) & 7) << 2)];
            }
#pragma unroll
            for (int j = 0; j < TN; ++j) {
                int r = tx + 16 * j;
                int rot = (r + (r >> 4)) & 7;
                wv[j] = *(const float4*)&Wt[r * 32 + (((gk + rot) & 7) << 2)];
            }
#pragma unroll
            for (int q = 0; q < 4; ++q)
#pragma unroll
                for (int i = 0; i < TM; ++i)
#pragma unroll
                    for (int j = 0; j < TN; ++j)
                        acc[i][j] = __builtin_fmaf(((const float*)&av[i])[q],
                                                   ((const float*)&wv[j])[q],
                                                   acc[i][j]);
        }

        // KC=512 restart: fold chain into join accumulator (plain add)
        if (((k0 + 32) & 511) == 0) {
#pragma unroll
            for (int i = 0; i < TM; ++i)
#pragma unroll
                for (int j = 0; j < TN; ++j) {
                    tot[i][j] = tot[i][j] + acc[i][j];
                    acc[i][j] = 0.0f;
                }
        }
    }

#pragma unroll
    for (int i = 0; i < TM; ++i)
#pragma unroll
        for (int j = 0; j < TN; ++j)
            C[(size_t)(m0 + ty + 16 * i) * N + (n0 + tx + 16 * j)] = tot[i][j];
}

// ---------- kernel 3: LIF scan over t for hidden layers (fp32, ref order) ----
__global__ __launch_bounds__(256) void k_scan_h(const float* __restrict__ Acc,
                                                const float* __restrict__ v_init,
                                                const float* __restrict__ s_init,
                                                const float* __restrict__ bias,
                                                float* __restrict__ Sout) {
    int idx = blockIdx.x * 256 + threadIdx.x;  // b*H + h
    int h = idx & (H_ - 1);
    float v = v_init[idx];
    float s = s_init[idx];
    float bb = bias[h];
#pragma unroll
    for (int t = 0; t < T_; ++t) {
        float x = Acc[(size_t)t * (B_ * H_) + idx];
        float d = 0.5f * v;          // exact (power of two)
        d = d * (1.0f - s);          // exact (x{0,1})
        v = d + x;
        v = v + bb;
        s = (v > 0.5f) ? 1.0f : 0.0f;
        Sout[(size_t)t * (B_ * H_) + idx] = s;
    }
}

// ---------- kernel 4: LIF scan + spike count for output layer ----------
__global__ __launch_bounds__(256) void k_scan_o(const float* __restrict__ Acc,
                                                const float* __restrict__ v_init,
                                                const float* __restrict__ s_init,
                                                const float* __restrict__ bias,
                                                float* __restrict__ out) {
    int idx = blockIdx.x * 256 + threadIdx.x;  // b*OUT + o
    int o = idx & (OUT_ - 1);
    float v = v_init[idx];
    float s = s_init[idx];
    float bb = bias[o];
    float acc = 0.0f;
#pragma unroll
    for (int t = 0; t < T_; ++t) {
        float x = Acc[(size_t)t * (B_ * OUT_) + idx];
        float d = 0.5f * v;
        d = d * (1.0f - s);
        v = d + x;
        v = v + bb;
        s = (v > 0.5f) ? 1.0f : 0.0f;
        acc += s;                    // integer-valued, exact in fp32
    }
    out[idx] = acc;
}

// ---------- launch ----------

extern "C" void kernel_launch(void* const* d_in, const int* in_sizes, int n_in,
                              void* d_out, int out_size, void* d_ws, size_t ws_size,
                              hipStream_t stream) {
    const float* spike_data = (const float*)d_in[0];
    const float* h0_volt  = (const float*)d_in[1];
    const float* h0_spike = (const float*)d_in[2];
    const float* h1_volt  = (const float*)d_in[3];
    const float* h1_spike = (const float*)d_in[4];
    const float* o_volt   = (const float*)d_in[5];
    const float* o_spike  = (const float*)d_in[6];
    const float* W0 = (const float*)d_in[7];
    const float* b0 = (const float*)d_in[8];
    const float* W1 = (const float*)d_in[9];
    const float* b1 = (const float*)d_in[10];
    const float* Wo = (const float*)d_in[11];
    const float* bo = (const float*)d_in[12];
    float* out = (float*)d_out;

    // workspace layout (96 MB)
    char* ws = (char*)d_ws;
    const size_t MB = (size_t)1 << 20;
    float* Xt = (float*)(ws);             // 32 MB [T*B][IN]; reused as S1
    float* S0 = (float*)(ws + 32 * MB);   // 32 MB [T*B][H]
    float* Ab = (float*)(ws + 64 * MB);   // 32 MB [T*B][H] (or [T*B][OUT])
    float* S1 = Xt;                       // Xt dead after GEMM0

    const int M = T_ * B_;   // 4096

    k_transpose<<<(B_ * IN_) / 256, 256, 0, stream>>>(spike_data, Xt);

    // hidden GEMMs: BM=128 BN=64, thread tile 8x4, 1024 blocks (4/CU)
    // layer 0: A0 = Xt @ W0^T   [4096,2048] x [2048,2048]
    k_gemm_pipe<128, 64, 8, 4, 4, 2>
        <<<dim3(H_ / 64, M / 128), 256, 0, stream>>>(Xt, W0, Ab, M, H_, IN_);
    k_scan_h<<<(B_ * H_) / 256, 256, 0, stream>>>(Ab, h0_volt, h0_spike, b0, S0);

    // layer 1: A1 = S0 @ W1^T
    k_gemm_pipe<128, 64, 8, 4, 4, 2>
        <<<dim3(H_ / 64, M / 128), 256, 0, stream>>>(S0, W1, Ab, M, H_, H_);
    k_scan_h<<<(B_ * H_) / 256, 256, 0, stream>>>(Ab, h1_volt, h1_spike, b1, S1);

    // output: Ao = S1 @ Wo^T   [4096,2048] x [2048,512], BM=BN=64 (512 blocks)
    k_gemm_pipe<64, 64, 4, 4, 2, 2>
        <<<dim3(OUT_ / 64, M / 64), 256, 0, stream>>>(S1, Wo, Ab, M, OUT_, H_);
    k_scan_o<<<(B_ * OUT_) / 256, 256, 0, stream>>>(Ab, o_volt, o_spike, bo, out);

    (void)in_sizes; (void)n_in; (void)out_size; (void)ws_size;
}

// Round 12
// 2545.072 us; speedup vs baseline: 1.4162x; 1.4162x over previous
//
#include <hip/hip_runtime.h>
#include <cstdint>

// Problem dims (fixed by reference)
#define B_   128
#define T_   32
#define IN_  2048
#define H_   2048
#define OUT_ 512

// ---------- kernel 1: transpose spikes ----------
__global__ __launch_bounds__(256) void k_transpose(const float* __restrict__ in,
                                                   float* __restrict__ Xt) {
    int idx = blockIdx.x * 256 + threadIdx.x;   // b*IN + i
    int b = idx >> 11;
    int i = idx & (IN_ - 1);
    const float4* p = (const float4*)(in + (size_t)idx * T_);
#pragma unroll
    for (int q = 0; q < 8; ++q) {
        float4 v = p[q];
        int t = q * 4;
        Xt[((size_t)((t + 0) * B_ + b) << 11) + i] = v.x;
        Xt[((size_t)((t + 1) * B_ + b) << 11) + i] = v.y;
        Xt[((size_t)((t + 2) * B_ + b) << 11) + i] = v.z;
        Xt[((size_t)((t + 3) * B_ + b) << 11) + i] = v.w;
    }
}

// ---------- kernel 2: fp32 GEMM, KC=512 chain (BLIS schedule), dbuf pipeline -
// VERIFIED bit-exact vs ref (R10, absmax 0): per C element ascending-k fp32
// FMA chain, accumulator restarts at k=512/1024/1536, restart partials joined
// to C by plain rounded adds in ascending order. DO NOT change the chain.
// Throughput structure (R12):
//  - double-buffered LDS, ONE barrier per k0-iter;
//  - tile k+1's global loads issued right after the barrier, consumed by
//    ds_write AFTER the compute -> ~2048 FMA cycles to hide global latency;
//  - NO waves/EU launch-bound (R11's (256,4) forced 64 VGPR -> spills to
//    scratch, 3 GB FETCH/dispatch, 1.5x regression. Let VGPR float ~170).
//  - LDS granule rotation: row r stores source granule s at slot ((s+rot(r))&7),
//    rot(r)=(r+(r>>4))&7 -> av reads broadcast, wv reads 2-way (free).
template <int BM, int BN, int TM, int TN, int GA, int GW>
__global__ __launch_bounds__(256)
void k_gemm_pipe(const float* __restrict__ A, const float* __restrict__ W,
                 float* __restrict__ C, int M, int N, int K) {
    __shared__ alignas(16) float At[2][BM * 32];
    __shared__ alignas(16) float Wt[2][BN * 32];

    const int tid = threadIdx.x;
    const int tx  = tid & 15;        // n direction
    const int ty  = tid >> 4;        // m direction
    const int m0  = blockIdx.y * BM;
    const int n0  = blockIdx.x * BN;

    float acc[TM][TN];               // in-block FMA chain (KC=512)
    float tot[TM][TN];               // cross-block joins (plain adds)
#pragma unroll
    for (int i = 0; i < TM; ++i)
#pragma unroll
        for (int j = 0; j < TN; ++j) { acc[i][j] = 0.0f; tot[i][j] = 0.0f; }

    float4 pa[GA], pw[GW];
    // prologue: load tile k0=0 and stage into buffer 0
#pragma unroll
    for (int u = 0; u < GA; ++u) {
        int g = tid + 256 * u, r = g >> 3, s = g & 7;
        pa[u] = *(const float4*)(A + (size_t)(m0 + r) * K + s * 4);
    }
#pragma unroll
    for (int u = 0; u < GW; ++u) {
        int g = tid + 256 * u, r = g >> 3, s = g & 7;
        pw[u] = *(const float4*)(W + (size_t)(n0 + r) * K + s * 4);
    }
#pragma unroll
    for (int u = 0; u < GA; ++u) {
        int g = tid + 256 * u, r = g >> 3, s = g & 7;
        int rot = (r + (r >> 4)) & 7;
        *(float4*)&At[0][r * 32 + (((s + rot) & 7) << 2)] = pa[u];
    }
#pragma unroll
    for (int u = 0; u < GW; ++u) {
        int g = tid + 256 * u, r = g >> 3, s = g & 7;
        int rot = (r + (r >> 4)) & 7;
        *(float4*)&Wt[0][r * 32 + (((s + rot) & 7) << 2)] = pw[u];
    }

    int p = 0;
    for (int k0 = 0; k0 < K; k0 += 32) {
        __syncthreads();             // buffer p fully staged
        const bool more = (k0 + 32) < K;

        // issue NEXT tile's global loads; they fly under the compute below
        if (more) {
            int kn = k0 + 32;
#pragma unroll
            for (int u = 0; u < GA; ++u) {
                int g = tid + 256 * u, r = g >> 3, s = g & 7;
                pa[u] = *(const float4*)(A + (size_t)(m0 + r) * K + kn + s * 4);
            }
#pragma unroll
            for (int u = 0; u < GW; ++u) {
                int g = tid + 256 * u, r = g >> 3, s = g & 7;
                pw[u] = *(const float4*)(W + (size_t)(n0 + r) * K + kn + s * 4);
            }
        }

        // compute: strictly ascending k, independent chain per C element
#pragma unroll
        for (int gk = 0; gk < 8; ++gk) {
            float4 av[TM], wv[TN];
#pragma unroll
            for (int i = 0; i < TM; ++i) {
                int r = ty + 16 * i;
                int rot = (r + (r >> 4)) & 7;
                av[i] = *(const float4*)&At[p][r * 32 + (((gk + rot) & 7) << 2)];
            }
#pragma unroll
            for (int j = 0; j < TN; ++j) {
                int r = tx + 16 * j;
                int rot = (r + (r >> 4)) & 7;
                wv[j] = *(const float4*)&Wt[p][r * 32 + (((gk + rot) & 7) << 2)];
            }
#pragma unroll
            for (int q = 0; q < 4; ++q)
#pragma unroll
                for (int i = 0; i < TM; ++i)
#pragma unroll
                    for (int j = 0; j < TN; ++j)
                        acc[i][j] = __builtin_fmaf(((const float*)&av[i])[q],
                                                   ((const float*)&wv[j])[q],
                                                   acc[i][j]);
        }

        // stage tile k+1 into the other buffer (loads have landed by now)
        if (more) {
#pragma unroll
            for (int u = 0; u < GA; ++u) {
                int g = tid + 256 * u, r = g >> 3, s = g & 7;
                int rot = (r + (r >> 4)) & 7;
                *(float4*)&At[1 - p][r * 32 + (((s + rot) & 7) << 2)] = pa[u];
            }
#pragma unroll
            for (int u = 0; u < GW; ++u) {
                int g = tid + 256 * u, r = g >> 3, s = g & 7;
                int rot = (r + (r >> 4)) & 7;
                *(float4*)&Wt[1 - p][r * 32 + (((s + rot) & 7) << 2)] = pw[u];
            }
        }

        // KC=512 restart: fold chain into join accumulator (plain add)
        if (((k0 + 32) & 511) == 0) {
#pragma unroll
            for (int i = 0; i < TM; ++i)
#pragma unroll
                for (int j = 0; j < TN; ++j) {
                    tot[i][j] = tot[i][j] + acc[i][j];
                    acc[i][j] = 0.0f;
                }
        }
        p ^= 1;
    }

#pragma unroll
    for (int i = 0; i < TM; ++i)
#pragma unroll
        for (int j = 0; j < TN; ++j)
            C[(size_t)(m0 + ty + 16 * i) * N + (n0 + tx + 16 * j)] = tot[i][j];
}

// ---------- kernel 3: LIF scan over t for hidden layers (fp32, ref order) ----
__global__ __launch_bounds__(256) void k_scan_h(const float* __restrict__ Acc,
                                                const float* __restrict__ v_init,
                                                const float* __restrict__ s_init,
                                                const float* __restrict__ bias,
                                                float* __restrict__ Sout) {
    int idx = blockIdx.x * 256 + threadIdx.x;  // b*H + h
    int h = idx & (H_ - 1);
    float v = v_init[idx];
    float s = s_init[idx];
    float bb = bias[h];
#pragma unroll
    for (int t = 0; t < T_; ++t) {
        float x = Acc[(size_t)t * (B_ * H_) + idx];
        float d = 0.5f * v;          // exact (power of two)
        d = d * (1.0f - s);          // exact (x{0,1})
        v = d + x;
        v = v + bb;
        s = (v > 0.5f) ? 1.0f : 0.0f;
        Sout[(size_t)t * (B_ * H_) + idx] = s;
    }
}

// ---------- kernel 4: LIF scan + spike count for output layer ----------
__global__ __launch_bounds__(256) void k_scan_o(const float* __restrict__ Acc,
                                                const float* __restrict__ v_init,
                                                const float* __restrict__ s_init,
                                                const float* __restrict__ bias,
                                                float* __restrict__ out) {
    int idx = blockIdx.x * 256 + threadIdx.x;  // b*OUT + o
    int o = idx & (OUT_ - 1);
    float v = v_init[idx];
    float s = s_init[idx];
    float bb = bias[o];
    float acc = 0.0f;
#pragma unroll
    for (int t = 0; t < T_; ++t) {
        float x = Acc[(size_t)t * (B_ * OUT_) + idx];
        float d = 0.5f * v;
        d = d * (1.0f - s);
        v = d + x;
        v = v + bb;
        s = (v > 0.5f) ? 1.0f : 0.0f;
        acc += s;                    // integer-valued, exact in fp32
    }
    out[idx] = acc;
}

// ---------- launch ----------

extern "C" void kernel_launch(void* const* d_in, const int* in_sizes, int n_in,
                              void* d_out, int out_size, void* d_ws, size_t ws_size,
                              hipStream_t stream) {
    const float* spike_data = (const float*)d_in[0];
    const float* h0_volt  = (const float*)d_in[1];
    const float* h0_spike = (const float*)d_in[2];
    const float* h1_volt  = (const float*)d_in[3];
    const float* h1_spike = (const float*)d_in[4];
    const float* o_volt   = (const float*)d_in[5];
    const float* o_spike  = (const float*)d_in[6];
    const float* W0 = (const float*)d_in[7];
    const float* b0 = (const float*)d_in[8];
    const float* W1 = (const float*)d_in[9];
    const float* b1 = (const float*)d_in[10];
    const float* Wo = (const float*)d_in[11];
    const float* bo = (const float*)d_in[12];
    float* out = (float*)d_out;

    // workspace layout (96 MB)
    char* ws = (char*)d_ws;
    const size_t MB = (size_t)1 << 20;
    float* Xt = (float*)(ws);             // 32 MB [T*B][IN]; reused as S1
    float* S0 = (float*)(ws + 32 * MB);   // 32 MB [T*B][H]
    float* Ab = (float*)(ws + 64 * MB);   // 32 MB [T*B][H] (or [T*B][OUT])
    float* S1 = Xt;                       // Xt dead after GEMM0

    const int M = T_ * B_;   // 4096

    k_transpose<<<(B_ * IN_) / 256, 256, 0, stream>>>(spike_data, Xt);

    // hidden GEMMs: BM=64 BN=128, thread tile 4x8 (R10-verified shape)
    // layer 0: A0 = Xt @ W0^T   [4096,2048] x [2048,2048]
    k_gemm_pipe<64, 128, 4, 8, 2, 4>
        <<<dim3(H_ / 128, M / 64), 256, 0, stream>>>(Xt, W0, Ab, M, H_, IN_);
    k_scan_h<<<(B_ * H_) / 256, 256, 0, stream>>>(Ab, h0_volt, h0_spike, b0, S0);

    // layer 1: A1 = S0 @ W1^T
    k_gemm_pipe<64, 128, 4, 8, 2, 4>
        <<<dim3(H_ / 128, M / 64), 256, 0, stream>>>(S0, W1, Ab, M, H_, H_);
    k_scan_h<<<(B_ * H_) / 256, 256, 0, stream>>>(Ab, h1_volt, h1_spike, b1, S1);

    // output: Ao = S1 @ Wo^T   [4096,2048] x [2048,512]
    k_gemm_pipe<64, 128, 4, 8, 2, 4>
        <<<dim3(OUT_ / 128, M / 64), 256, 0, stream>>>(S1, Wo, Ab, M, OUT_, H_);
    k_scan_o<<<(B_ * OUT_) / 256, 256, 0, stream>>>(Ab, o_volt, o_spike, bo, out);

    (void)in_sizes; (void)n_in; (void)out_size; (void)ws_size;
}